// Round 3
// baseline (33.118 us; speedup 1.0000x reference)
//
#include <hip/hip_runtime.h>
#include <math.h>

#define T_LEN 1600
#define D_DIM 64
#define WIN   50
#define NPT   48            // N = WINDOW - (TAK_DIM-1)*TAK_TAU
#define LDW   49            // LDS row stride (conflict-free scalar row reads)
#define NPAIR 1128          // N*(N-1)/2 unique pairs
#define VPL   18            // ceil(1128/64) values per lane for median wave
#define K_MED 563           // lower-median rank among 1128 unique pair dists

// H1 features (beta1_med, ent1, maxp1, land1) are identically zero:
// beta1(r) = edges - N + comps is the graph cycle rank, monotone
// non-decreasing along the sorted-radii filtration, so `ends` never fires.
// Only H0 + the pair-distance median matter. All H0 features depend only on
// the MULTISET of MST edge weights, and every MST of a weighted graph has
// the same weight multiset => Boruvka (parallel, ~5 rounds) replaces Prim
// (47 serial rounds) with bit-identical feature values. Unique u64 keys
// (weight bits << 12 | edge id) make the MST unique => no tie hazards.
__global__ __launch_bounds__(256)
void topo_feats_kernel(const float* __restrict__ latent,
                       const float* __restrict__ W,
                       const float* __restrict__ bvec,
                       float* __restrict__ out)
{
    __shared__ float              s_series[WIN];
    __shared__ float              s_sq[NPT];
    __shared__ float              s_Dp[NPT * LDW];
    __shared__ unsigned long long s_best[NPT];
    __shared__ int                s_comp[NPT];
    __shared__ int                s_parent[NPT];
    __shared__ float              s_deaths[NPT - 1];
    __shared__ int                s_ndeaths;
    __shared__ float              s_med;

    const int w   = blockIdx.x;          // window id
    const int bb  = w >> 5;              // batch
    const int kk  = w & 31;              // window within batch
    const int tid = threadIdx.x;

    // ---- P1a. wave 0: series norms (8-acc, bit-identical to passing ver);
    //           s_sq via shuffles. wave 1: init comp labels / death counter.
    if (tid < 64) {
        const int lane = tid;
        float x0 = 0.0f;
        if (lane < WIN) {
            const float* p = latent + ((size_t)bb * T_LEN + (size_t)kk * WIN + lane) * D_DIM;
            float r[8];
#pragma unroll
            for (int q = 0; q < 8; ++q) r[q] = 0.0f;
#pragma unroll
            for (int i = 0; i < D_DIM; i += 8)
#pragma unroll
                for (int q = 0; q < 8; ++q)
                    r[q] = __fadd_rn(r[q], __fmul_rn(p[i + q], p[i + q]));
            float ss = __fadd_rn(__fadd_rn(__fadd_rn(r[0], r[1]), __fadd_rn(r[2], r[3])),
                                 __fadd_rn(__fadd_rn(r[4], r[5]), __fadd_rn(r[6], r[7])));
            x0 = sqrtf(ss);
        }
        float x1 = __shfl_down(x0, 1);
        float x2 = __shfl_down(x0, 2);
        if (lane < WIN) s_series[lane] = x0;
        if (lane < NPT)
            s_sq[lane] = __fadd_rn(__fadd_rn(__fmul_rn(x0, x0), __fmul_rn(x1, x1)),
                                   __fmul_rn(x2, x2));
    } else if (tid < 128) {
        const int l = tid - 64;
        if (l < NPT) s_comp[l] = l;
        if (l == NPT) s_ndeaths = 0;
    }
    __syncthreads();

    // ---- P1b. pairwise distances (arithmetic identical to passing version)
    for (int e = tid; e < NPT * NPT; e += 256) {
        int i = e / NPT, j = e - i * NPT;
        float dot = fmaf(s_series[i + 2], s_series[j + 2],
                    fmaf(s_series[i + 1], s_series[j + 1],
                         __fmul_rn(s_series[i], s_series[j])));
        float d2 = __fsub_rn(__fadd_rn(s_sq[i], s_sq[j]), __fmul_rn(2.0f, dot));
        s_Dp[i * LDW + j] = sqrtf(fmaxf(d2, 0.0f));
    }
    __syncthreads();

    const int wv   = tid >> 6;
    const int lane = tid & 63;

    if (wv == 0) {
        // ---- P2a. Boruvka MST: 6 rounds, wave-0 only (no barriers needed;
        //           LDS ops within a wave are program-ordered).
        for (int round = 0; round < 6; ++round) {
            if (lane < NPT) s_best[lane] = ~0ull;

            unsigned long long best = ~0ull;
            int myc = 0;
            if (lane < NPT) {
                myc = s_comp[lane];
#pragma unroll 8
                for (int j = 0; j < NPT; ++j) {
                    int   cj = s_comp[j];                 // broadcast read
                    float dv = s_Dp[lane * LDW + j];      // conflict-free row
                    if (cj != myc) {
                        unsigned eid = (lane < j) ? (unsigned)(lane * NPT + j)
                                                  : (unsigned)(j * NPT + lane);
                        unsigned long long k =
                            ((unsigned long long)__float_as_uint(dv) << 12) | eid;
                        best = (k < best) ? k : best;
                    }
                }
                if (best != ~0ull) atomicMin(&s_best[myc], best);
            }

            // merge phase: one lane per component label
            if (lane < NPT) s_parent[lane] = lane;
            bool live = (lane < NPT) && (s_comp[lane] == lane);
            unsigned long long bk = live ? s_best[lane] : ~0ull;
            int other = lane;
            if (live && bk != ~0ull) {
                unsigned wb  = (unsigned)(bk >> 12);
                int      eid = (int)(bk & 0xFFFu);
                int a = eid / NPT, b = eid - NPT * a;
                int ca = s_comp[a], cb = s_comp[b];
                other = (ca == lane) ? cb : ca;
                bool rec = !((s_best[other] == bk) && (other < lane));
                if (rec) {
                    int sl = atomicAdd(&s_ndeaths, 1);
                    s_deaths[sl] = __uint_as_float(wb);
                }
                s_parent[lane] = other;
            }
            // break mutual 2-cycles: smaller label becomes root
            if (live && bk != ~0ull) {
                if (s_parent[other] == lane && lane < other) s_parent[lane] = lane;
            }
            // pointer jumping (depth <= 48 -> 6 doublings)
#pragma unroll
            for (int k = 0; k < 6; ++k) {
                if (lane < NPT) {
                    int p = s_parent[lane];
                    int g = s_parent[p];
                    s_parent[lane] = g;
                }
            }
            if (lane < NPT) s_comp[lane] = s_parent[s_comp[lane]];
        }
    } else if (wv == 1) {
        // ---- P2b. exact median of 1128 unique pair distances via bitwise
        //           binary search; counts via ballot+popc (no ds_swizzle).
        unsigned ub[VPL];
#pragma unroll
        for (int r = 0; r < VPL; ++r) {
            int e = lane + 64 * r;
            unsigned v = 0xFFFFFFFFu;                 // sentinel: never < probe
            if (e < NPAIR) {
                int i = 0, rem = e;
                while (rem >= NPT - 1 - i) { rem -= NPT - 1 - i; ++i; }
                int j = i + 1 + rem;
                v = __float_as_uint(s_Dp[i * LDW + j]);
            }
            ub[r] = v;
        }
        unsigned lo = 0;
        for (int bit = 30; bit >= 0; --bit) {
            unsigned probe = lo | (1u << bit);
            int c = 0;
#pragma unroll
            for (int r = 0; r < VPL; ++r)
                c += __popcll(__ballot(ub[r] < probe));
            if (c <= K_MED) lo = probe;
        }
        const unsigned v0 = lo;                        // rank-563 value
        int cle = 0; unsigned mn = 0xFFFFFFFFu;
#pragma unroll
        for (int r = 0; r < VPL; ++r) {
            cle += __popcll(__ballot(ub[r] <= v0));
            if (ub[r] > v0 && ub[r] < mn) mn = ub[r];
        }
#pragma unroll
        for (int off = 32; off > 0; off >>= 1) {
            unsigned m2 = (unsigned)__shfl_xor((int)mn, off);
            mn = (m2 < mn) ? m2 : mn;
        }
        unsigned v1 = (cle >= K_MED + 2) ? v0 : mn;    // rank-564 value
        if (lane == 0)
            s_med = __fadd_rn(__fmul_rn(0.5f, __uint_as_float(v0)),
                              __fmul_rn(0.5f, __uint_as_float(v1)));
    }
    __syncthreads();

    // ---- P3. wave-parallel H0 features + linear head (wave 0).
    //          All features are order-free over the deaths multiset.
    if (wv == 0) {
        const float rmed = s_med;
        const bool  isd  = (lane < NPT - 1);
        const float d    = isd ? s_deaths[lane] : 0.0f;

        float beta0 = (float)__popcll(__ballot(isd && (d > rmed)));

        float mx = isd ? d : -INFINITY;
#pragma unroll
        for (int off = 32; off > 0; off >>= 1)
            mx = fmaxf(mx, __shfl_xor(mx, off));

        float sv = (isd && d > 0.0f) ? d : 0.0f;
        float ss = sv;
#pragma unroll
        for (int off = 32; off > 0; off >>= 1) ss += __shfl_xor(ss, off);

        float p    = sv / ss;
        float term = (p > 0.0f) ? -p * logf(p) : 0.0f;
        float ent  = term;
#pragma unroll
        for (int off = 32; off > 0; off >>= 1) ent += __shfl_xor(ent, off);

        // landscape: births=0 => lam(t) = clamp(min(t, mx - t)), t in [0,mx]
        float step = mx / 19.0f;
        float t    = step * (float)lane;
        float lam  = (lane < 20) ? fmaxf(fminf(t, mx - t), 0.0f) : 0.0f;
        float land = lam;
#pragma unroll
        for (int off = 32; off > 0; off >>= 1) land += __shfl_xor(land, off);
        land *= (1.0f / 20.0f);

        // feats = [beta0, 0, ent0, 0, maxp0, 0, land0, 0] @ W.T + b
        if (lane < 8) {
            float o = bvec[lane]
                    + beta0 * W[lane * 8 + 0]
                    + ent   * W[lane * 8 + 2]
                    + mx    * W[lane * 8 + 4]
                    + land  * W[lane * 8 + 6];
            out[w * 8 + lane] = o;
        }
    }
}

extern "C" void kernel_launch(void* const* d_in, const int* in_sizes, int n_in,
                              void* d_out, int out_size, void* d_ws, size_t ws_size,
                              hipStream_t stream)
{
    const float* latent = (const float*)d_in[0];
    const float* W      = (const float*)d_in[1];
    const float* bvec   = (const float*)d_in[2];
    float*       out    = (float*)d_out;

    topo_feats_kernel<<<dim3(256), dim3(256), 0, stream>>>(latent, W, bvec, out);

    (void)in_sizes; (void)n_in; (void)out_size; (void)d_ws; (void)ws_size;
}

// Round 4
// 19.002 us; speedup vs baseline: 1.7428x; 1.7428x over previous
//
#include <hip/hip_runtime.h>
#include <math.h>

#define T_LEN 1600
#define D_DIM 64
#define WIN   50
#define NPT   48            // N = WINDOW - (TAK_DIM-1)*TAK_TAU
#define NPAIR 1128          // N*(N-1)/2 unique pairs
#define VPL   18            // ceil(1128/64) values per lane for median wave
#define K_MED 563           // lower-median rank among 1128 unique pair dists

// H1 features (beta1_med, ent1, maxp1, land1) are identically zero:
// beta1(r) = edges - N + comps is the graph cycle rank, monotone
// non-decreasing along the sorted-radii filtration, so `ends` never fires.
// Only H0 (Prim MST deaths) + the pair-distance median matter.
//
// DPP wave reduction (rocPRIM-style masked sequence). Every written lane
// has a valid fetch in every step (quad_perm always valid; shr/bcast steps
// write-masked to valid lanes only), so bound_ctrl semantics are moot and
// the same sequence is correct for min, max and sum. Result lands in lane
// 63; broadcast via readlane.
template <typename F>
__device__ __forceinline__ int dpp_red63(int v, F op) {
    int t;
    t = __builtin_amdgcn_update_dpp(v, v, 0xb1, 0xf, 0xf, false); v = op(v, t); // quad [1,0,3,2]
    t = __builtin_amdgcn_update_dpp(v, v, 0x4e, 0xf, 0xf, false); v = op(v, t); // quad [2,3,0,1]
    t = __builtin_amdgcn_update_dpp(v, v, 0x114, 0xf, 0xe, false); v = op(v, t); // row_shr:4
    t = __builtin_amdgcn_update_dpp(v, v, 0x118, 0xf, 0xc, false); v = op(v, t); // row_shr:8
    t = __builtin_amdgcn_update_dpp(v, v, 0x142, 0xa, 0xf, false); v = op(v, t); // row_bcast:15
    t = __builtin_amdgcn_update_dpp(v, v, 0x143, 0xc, 0xf, false); v = op(v, t); // row_bcast:31
    return v;
}
__device__ __forceinline__ float wave_fmin_bc(float v) {
    int r = dpp_red63(__float_as_int(v), [](int a, int b) {
        return __float_as_int(fminf(__int_as_float(a), __int_as_float(b))); });
    return __int_as_float(__builtin_amdgcn_readlane(r, 63));
}
__device__ __forceinline__ float wave_fmax_bc(float v) {
    int r = dpp_red63(__float_as_int(v), [](int a, int b) {
        return __float_as_int(fmaxf(__int_as_float(a), __int_as_float(b))); });
    return __int_as_float(__builtin_amdgcn_readlane(r, 63));
}
__device__ __forceinline__ float wave_fadd_bc(float v) {
    int r = dpp_red63(__float_as_int(v), [](int a, int b) {
        return __float_as_int(__fadd_rn(__int_as_float(a), __int_as_float(b))); });
    return __int_as_float(__builtin_amdgcn_readlane(r, 63));
}
__device__ __forceinline__ unsigned wave_umin_bc(unsigned v) {
    int r = dpp_red63((int)v, [](int a, int b) {
        unsigned ua = (unsigned)a, ub = (unsigned)b;
        return (int)(ua < ub ? ua : ub); });
    return (unsigned)__builtin_amdgcn_readlane(r, 63);
}

__global__ __launch_bounds__(256)
void topo_feats_kernel(const float* __restrict__ latent,
                       const float* __restrict__ W,
                       const float* __restrict__ bvec,
                       float* __restrict__ out)
{
    __shared__ float s_series[WIN];
    __shared__ float s_sq[NPT];
    __shared__ float s_D[NPT * NPT];
    __shared__ float s_med;

    const int w   = blockIdx.x;          // window id
    const int bb  = w >> 5;              // batch
    const int kk  = w & 31;              // window within batch
    const int tid = threadIdx.x;

    // ---- P1a. wave 0: series norms (8-acc, arithmetic identical to the
    //           passing versions); s_sq via shfl_down (also proven in R3).
    if (tid < 64) {
        const int lane = tid;
        float x0 = 0.0f;
        if (lane < WIN) {
            const float* p = latent + ((size_t)bb * T_LEN + (size_t)kk * WIN + lane) * D_DIM;
            float r[8];
#pragma unroll
            for (int q = 0; q < 8; ++q) r[q] = 0.0f;
#pragma unroll
            for (int i = 0; i < D_DIM; i += 8)
#pragma unroll
                for (int q = 0; q < 8; ++q)
                    r[q] = __fadd_rn(r[q], __fmul_rn(p[i + q], p[i + q]));
            float ss = __fadd_rn(__fadd_rn(__fadd_rn(r[0], r[1]), __fadd_rn(r[2], r[3])),
                                 __fadd_rn(__fadd_rn(r[4], r[5]), __fadd_rn(r[6], r[7])));
            x0 = sqrtf(ss);
        }
        float x1 = __shfl_down(x0, 1);
        float x2 = __shfl_down(x0, 2);
        if (lane < WIN) s_series[lane] = x0;
        if (lane < NPT)
            s_sq[lane] = __fadd_rn(__fadd_rn(__fmul_rn(x0, x0), __fmul_rn(x1, x1)),
                                   __fmul_rn(x2, x2));
    }
    __syncthreads();

    // ---- P1b. pairwise distances (arithmetic identical to passing version)
    for (int e = tid; e < NPT * NPT; e += 256) {
        int i = e / NPT, j = e - i * NPT;
        float dot = fmaf(s_series[i + 2], s_series[j + 2],
                    fmaf(s_series[i + 1], s_series[j + 1],
                         __fmul_rn(s_series[i], s_series[j])));
        float d2 = __fsub_rn(__fadd_rn(s_sq[i], s_sq[j]), __fmul_rn(2.0f, dot));
        s_D[i * NPT + j] = sqrtf(fmaxf(d2, 0.0f));
    }
    __syncthreads();

    const int wv   = tid >> 6;
    const int lane = tid & 63;
    float dreg = 0.0f;                   // lane `it` holds MST death `it`

    if (wv == 0) {
        // ---- P2a. Prim MST deaths; DPP argmin (~200cy/iter vs ~400 shfl)
        bool  intree = (lane == 0);
        float mind   = (lane < NPT) ? s_D[lane] : 1e30f;   // row 0
        for (int it = 0; it < NPT - 1; ++it) {
            float cand = (intree || lane >= NPT) ? 1e30f : mind;
            float wmin = wave_fmin_bc(cand);               // uniform (SGPR)
            if (lane == it) dreg = wmin;
            // lowest-index argmin (== jnp.argmin; multiset tie-invariant)
            unsigned long long m = __ballot(cand == wmin);
            int id = __ffsll(m) - 1;
            if (lane == id) intree = true;
            if (lane < NPT) mind = fminf(mind, s_D[id * NPT + lane]);
        }
    } else if (wv == 1) {
        // ---- P2b. exact median of 1128 unique pair distances via bitwise
        //           binary search; counts via ballot+popc. Triangular decode
        //           closed-form: 9025-8*off(i) = (95-2i)^2 exactly.
        unsigned ub[VPL];
#pragma unroll
        for (int r = 0; r < VPL; ++r) {
            int e = lane + 64 * r;
            unsigned v = 0xFFFFFFFFu;                 // sentinel: never < probe
            if (e < NPAIR) {
                int i = (int)((95.0f - sqrtf((float)(9025 - 8 * e))) * 0.5f);
                i = (i < 0) ? 0 : ((i > NPT - 2) ? NPT - 2 : i);
                int offi = (i * (95 - i)) >> 1;
                int offn = ((i + 1) * (94 - i)) >> 1;
                if (e >= offn)      { ++i; offi = offn; }
                else if (e < offi)  { --i; offi = (i * (95 - i)) >> 1; }
                int j = i + 1 + (e - offi);
                v = __float_as_uint(s_D[i * NPT + j]);
            }
            ub[r] = v;
        }
        unsigned lo = 0;
        for (int bit = 30; bit >= 0; --bit) {
            unsigned probe = lo | (1u << bit);
            int c = 0;
#pragma unroll
            for (int r = 0; r < VPL; ++r)
                c += __popcll(__ballot(ub[r] < probe));
            if (c <= K_MED) lo = probe;
        }
        const unsigned v0 = lo;                        // rank-563 value
        int cle = 0; unsigned mn = 0xFFFFFFFFu;
#pragma unroll
        for (int r = 0; r < VPL; ++r) {
            cle += __popcll(__ballot(ub[r] <= v0));
            if (ub[r] > v0 && ub[r] < mn) mn = ub[r];
        }
        mn = wave_umin_bc(mn);
        unsigned v1 = (cle >= K_MED + 2) ? v0 : mn;    // rank-564 value
        if (lane == 0)
            s_med = __fadd_rn(__fmul_rn(0.5f, __uint_as_float(v0)),
                              __fmul_rn(0.5f, __uint_as_float(v1)));
    }
    __syncthreads();

    // ---- P3. wave-parallel H0 features + linear head (wave 0)
    if (wv == 0) {
        const float rmed = s_med;
        const bool  isd  = (lane < NPT - 1);
        const float d    = isd ? dreg : 0.0f;

        float beta0 = (float)__popcll(__ballot(isd && (d > rmed)));
        float mx    = wave_fmax_bc(isd ? d : -INFINITY);

        float sv = (isd && d > 0.0f) ? d : 0.0f;
        float ss = wave_fadd_bc(sv);

        float p    = sv / ss;                          // ss > 0 always here
        float term = (p > 0.0f) ? -p * logf(p) : 0.0f;
        float ent  = wave_fadd_bc(term);

        // landscape: births=0 => lam(t) = clamp(min(t, mx - t)), t in [0,mx]
        float step = mx / 19.0f;
        float t    = step * (float)lane;
        float lam  = (lane < 20) ? fmaxf(fminf(t, mx - t), 0.0f) : 0.0f;
        float land = wave_fadd_bc(lam) * (1.0f / 20.0f);

        // feats = [beta0, 0, ent0, 0, maxp0, 0, land0, 0] @ W.T + b
        if (lane < 8) {
            float o = bvec[lane]
                    + beta0 * W[lane * 8 + 0]
                    + ent   * W[lane * 8 + 2]
                    + mx    * W[lane * 8 + 4]
                    + land  * W[lane * 8 + 6];
            out[w * 8 + lane] = o;
        }
    }
}

extern "C" void kernel_launch(void* const* d_in, const int* in_sizes, int n_in,
                              void* d_out, int out_size, void* d_ws, size_t ws_size,
                              hipStream_t stream)
{
    const float* latent = (const float*)d_in[0];
    const float* W      = (const float*)d_in[1];
    const float* bvec   = (const float*)d_in[2];
    float*       out    = (float*)d_out;

    topo_feats_kernel<<<dim3(256), dim3(256), 0, stream>>>(latent, W, bvec, out);

    (void)in_sizes; (void)n_in; (void)out_size; (void)d_ws; (void)ws_size;
}